// Round 2
// baseline (1839.738 us; speedup 1.0000x reference)
//
#include <hip/hip_runtime.h>

typedef _Float16 h2   __attribute__((ext_vector_type(2)));
typedef _Float16 h4   __attribute__((ext_vector_type(4)));
typedef _Float16 half8 __attribute__((ext_vector_type(8)));
typedef float f32x4   __attribute__((ext_vector_type(4)));

#define MFMA16(a,b,c) __builtin_amdgcn_mfma_f32_16x16x32_f16((a),(b),(c),0,0,0)

// B=512, T=64, STOCH=30, DETER=200, HIDDEN=200, A=12, EMBED=1024
// out row = [stoch_po(30), mean_po(30), std_po(30), stoch_pr(30), mean_pr(30), std_pr(30), deter(200)] = 380

// Fragment regions (1KB blocks = 64 lanes x 8 halves), B-frag order [nt][ks][lane][8]
// INP:  NT=13 KS=2   base 0    (26)
// GRU:  NT=38 KS=13  base 26   (494)
// IMG:  NT=13 KS=7   base 520  (91)
// OBSD: NT=13 KS=7   base 611  (91)
// IMS:  NT=4  KS=7   base 702  (28)
// OBS:  NT=4  KS=7   base 730  (28)
// W2:   NT=13 KS=32  base 758  (416)  -> 1174 blocks
#define EP_HALVES ((size_t)32768*208)

__global__ void prep_frags(const float* __restrict__ inpW, const float* __restrict__ gruW,
                           const float* __restrict__ imgW, const float* __restrict__ obsoutW,
                           const float* __restrict__ imsW, const float* __restrict__ obsW,
                           _Float16* __restrict__ frags) {
    int gb = blockIdx.x, lane = threadIdx.x;
    const float* src; int KS, K, N, ld, roff = 0, local;
    if (gb < 26)       { src = inpW;    KS = 2;  K = 42;   N = 200; ld = 200; local = gb; }
    else if (gb < 520) { src = gruW;    KS = 13; K = 400;  N = 600; ld = 600; local = gb - 26; }
    else if (gb < 611) { src = imgW;    KS = 7;  K = 200;  N = 200; ld = 200; local = gb - 520; }
    else if (gb < 702) { src = obsoutW; KS = 7;  K = 200;  N = 200; ld = 200; local = gb - 611; }
    else if (gb < 730) { src = imsW;    KS = 7;  K = 200;  N = 60;  ld = 60;  local = gb - 702; }
    else if (gb < 758) { src = obsW;    KS = 7;  K = 200;  N = 60;  ld = 60;  local = gb - 730; }
    else               { src = obsoutW; KS = 32; K = 1024; N = 200; ld = 200; roff = 200; local = gb - 758; }
    int nt = local / KS, ks = local % KS;
    int n  = nt * 16 + (lane & 15);
    int k0 = ks * 32 + (lane >> 4) * 8;
    half8 v;
#pragma unroll
    for (int j = 0; j < 8; ++j) {
        int k = k0 + j;
        float f = (k < K && n < N) ? src[(size_t)(k + roff) * ld + n] : 0.0f;
        v[j] = (_Float16)f;
    }
    *(half8*)(frags + (size_t)gb * 512 + lane * 8) = v;
}

__global__ __launch_bounds__(256) void ep_gemm(const float* __restrict__ embed,
                                               const _Float16* __restrict__ w2f,
                                               _Float16* __restrict__ ep) {
    __shared__ __align__(16) _Float16 aE[16 * 1048];
    int tid = threadIdx.x;
    int rb = blockIdx.x * 16;
    for (int i = 0; i < 16; ++i) {
        float4 e = *((const float4*)(embed + (size_t)(rb + i) * 1024) + tid);
        h4 hv; hv[0] = (_Float16)e.x; hv[1] = (_Float16)e.y; hv[2] = (_Float16)e.z; hv[3] = (_Float16)e.w;
        *(h4*)(aE + i * 1048 + tid * 4) = hv;
    }
    __syncthreads();
    int w = tid >> 6, lane = tid & 63, m = lane & 15, q = lane >> 4;
    f32x4 acc[4] = {};
    int nts[4]; int ntc = 0;
    for (int nt = w; nt < 13; nt += 4) nts[ntc++] = nt;
    for (int ks = 0; ks < 32; ++ks) {
        half8 a = *(const half8*)(aE + m * 1048 + ks * 32 + q * 8);
#pragma unroll
        for (int j = 0; j < 4; ++j) if (j < ntc) {
            half8 b = *(const half8*)(w2f + ((size_t)(nts[j] * 32 + ks) * 64 + lane) * 8);
            acc[j] = MFMA16(a, b, acc[j]);
        }
    }
    for (int j = 0; j < ntc; ++j) {
        int col = nts[j] * 16 + m;
#pragma unroll
        for (int i = 0; i < 4; ++i)
            ep[(size_t)(rb + q * 4 + i) * 208 + col] = (_Float16)acc[j][i];
    }
}

__device__ __forceinline__ float sigm_(float x) { return 1.0f / (1.0f + __expf(-x)); }
__device__ __forceinline__ float tanh_(float x) { float e = __expf(2.0f * x); return 1.0f - 2.0f / (e + 1.0f); }
__device__ __forceinline__ float elu_(float x)  { return x > 0.0f ? x : __expf(x) - 1.0f; }
__device__ __forceinline__ float sp_(float x)   { return fmaxf(x, 0.0f) + log1pf(__expf(-fabsf(x))); }
__device__ __forceinline__ unsigned packh2(float a, float b) {
    h2 p; p[0] = (_Float16)a; p[1] = (_Float16)b;
    return __builtin_bit_cast(unsigned, p);
}

// One WG = 16 batch rows, 64 steps, 16 waves. 32 WGs cover B=512.
__global__ __launch_bounds__(1024) void rssm_scan(
    const float* __restrict__ action, const float* __restrict__ npr, const float* __restrict__ npo,
    const float* __restrict__ inp_b, const float* __restrict__ gru_b,
    const float* __restrict__ img_b, const float* __restrict__ obsout_b,
    const float* __restrict__ ims_b, const float* __restrict__ obs_b,
    const _Float16* __restrict__ frags, const _Float16* __restrict__ ep,
    float* __restrict__ out) {

    __shared__ __align__(16) unsigned actI[16 * 36];    // [stoch(15p) action(6p) zeropad], stride 36dw
    __shared__ __align__(16) unsigned actG[16 * 212];   // [x(100p) deter(100p) zeropad]
    __shared__ __align__(16) unsigned actH[16 * 116];   // h
    __shared__ __align__(16) unsigned actHO[16 * 116];  // ho
    __shared__ __align__(16) _Float16 parts[16 * 616];  // matmul outputs (f16)
    __shared__ float bias[1320];  // inp200 | gru600 | img200 | obsout200 | ims60 | obs60

    const _Float16* Finp  = frags;
    const _Float16* Fgru  = frags + (size_t)26  * 512;
    const _Float16* Fimg  = frags + (size_t)520 * 512;
    const _Float16* Fobsd = frags + (size_t)611 * 512;
    const _Float16* Fims  = frags + (size_t)702 * 512;
    const _Float16* Fobs  = frags + (size_t)730 * 512;

    int tid = threadIdx.x;
    int w = tid >> 6, lane = tid & 63, m = lane & 15, q = lane >> 4;
    int rb = blockIdx.x * 16;

    for (int i = tid; i < 1320; i += 1024) {
        float v;
        if (i < 200) v = inp_b[i];
        else if (i < 800)  v = gru_b[i - 200];
        else if (i < 1000) v = img_b[i - 800];
        else if (i < 1200) v = obsout_b[i - 1000];
        else if (i < 1260) v = ims_b[i - 1200];
        else               v = obs_b[i - 1260];
        bias[i] = v;
    }
    for (int i = tid; i < 16 * 36;  i += 1024) actI[i] = 0u;
    for (int i = tid; i < 16 * 212; i += 1024) actG[i] = 0u;
    for (int i = tid; i < 16 * 116; i += 1024) { actH[i] = 0u; actHO[i] = 0u; }

    // persistent register-resident weights: INP for waves 0..12, IMS/OBS for waves 0..7
    half8 binp[2];
    if (w < 13) {
#pragma unroll
        for (int ks = 0; ks < 2; ++ks)
            binp[ks] = *(const half8*)(Finp + ((size_t)(w * 2 + ks) * 64 + lane) * 8);
    }
    half8 bst[7];
    if (w < 8) {
        const _Float16* F = (w < 4) ? Fims : Fobs;
        int nt4 = w & 3;
#pragma unroll
        for (int ks = 0; ks < 7; ++ks)
            bst[ks] = *(const half8*)(F + ((size_t)(nt4 * 7 + ks) * 64 + lane) * 8);
    }
    __syncthreads();
    if (tid < 96) {  // pack action for t=0
        int r = tid / 6, cp = tid % 6;
        float2 a2 = *(const float2*)(action + ((size_t)(rb + r) * 64 + 0) * 12 + 2 * cp);
        actI[r * 36 + 15 + cp] = packh2(a2.x, a2.y);
    }
    // P5 thread mapping (fixed per thread)
    int p5_side = tid / 240, p5_rem = tid % 240, p5_r = p5_rem / 15, p5_cp = p5_rem % 15;
    const float* p5_nsrc = (p5_side == 0) ? npr : npo;
    __syncthreads();

    for (int t = 0; t < 64; ++t) {
        // ---- P1: x = elu(cat(stoch,action) @ inp_W + b), fused pack into actG[0..99] ----
        if (w < 13) {
            f32x4 acc = {};
#pragma unroll
            for (int ks = 0; ks < 2; ++ks) {
                half8 a = *(const half8*)(actI + m * 36 + ks * 16 + q * 4);
                acc = MFMA16(a, binp[ks], acc);
            }
            f32x4 accN;
#pragma unroll
            for (int i = 0; i < 4; ++i) accN[i] = __shfl_xor(acc[i], 1);
            if (!(m & 1)) {
                int col = w * 16 + m;
                if (col < 200) {
#pragma unroll
                    for (int i = 0; i < 4; ++i)
                        actG[(q * 4 + i) * 212 + (col >> 1)] =
                            packh2(elu_(acc[i] + bias[col]), elu_(accN[i] + bias[col + 1]));
                }
            }
        }
        __syncthreads();  // A

        // ---- P2: parts = cat(x, deter) @ gru_W  (38 tiles, KS=13) ----
        {
            int ntc = (w < 6) ? 3 : 2;
#pragma unroll
            for (int j = 0; j < 3; ++j) if (j < ntc) {
                int nt = w + 16 * j;
                half8 b[13];
#pragma unroll
                for (int ks = 0; ks < 13; ++ks)
                    b[ks] = *(const half8*)(Fgru + ((size_t)(nt * 13 + ks) * 64 + lane) * 8);
                f32x4 acc = {};
#pragma unroll
                for (int ks = 0; ks < 13; ++ks) {
                    half8 a = *(const half8*)(actG + m * 212 + ks * 16 + q * 4);
                    acc = MFMA16(a, b[ks], acc);
                }
                _Float16* pw = parts + q * 4 * 616 + nt * 16 + m;
#pragma unroll
                for (int i = 0; i < 4; ++i) pw[i * 616] = (_Float16)acc[i];
            }
        }
        __syncthreads();  // B

        // ---- gates: GRU update -> deter_new (actG[100..199]) + out[180..379] ----
        for (int idx = tid; idx < 1600; idx += 1024) {
            int r = idx / 100, cp = idx % 100;
            const _Float16* pr = parts + r * 616;
            h2 p0 = *(const h2*)(pr + 2 * cp);
            h2 p1 = *(const h2*)(pr + 200 + 2 * cp);
            h2 p2 = *(const h2*)(pr + 400 + 2 * cp);
            h2 dold = *(const h2*)&actG[r * 212 + 100 + cp];
            float dn[2];
#pragma unroll
            for (int e = 0; e < 2; ++e) {
                int n = 2 * cp + e;
                float reset = sigm_((float)p0[e] + bias[200 + n]);
                float cand  = tanh_(reset * ((float)p1[e] + bias[400 + n]));
                float upd   = sigm_((float)p2[e] + bias[600 + n] - 1.0f);
                dn[e] = upd * cand + (1.0f - upd) * (float)dold[e];
            }
            actG[r * 212 + 100 + cp] = packh2(dn[0], dn[1]);
            *(float2*)(out + ((size_t)(rb + r) * 64 + t) * 380 + 180 + 2 * cp) = make_float2(dn[0], dn[1]);
        }
        __syncthreads();  // C

        // prefetch for P5 (drains behind P3's streaming)
        float2 p5_nz, p0_a2;
        if (tid < 480)
            p5_nz = *(const float2*)(p5_nsrc + ((size_t)(rb + p5_r) * 64 + t) * 30 + 2 * p5_cp);
        if (tid < 96 && t < 63)
            p0_a2 = *(const float2*)(action + ((size_t)(rb + tid / 6) * 64 + (t + 1)) * 12 + 2 * (tid % 6));

        // ---- P3: h/ho preacts (26 tiles, KS=7), fused elu-pack into actH/actHO ----
        {
            int ntc3 = (w < 10) ? 2 : 1;
            h2 epv[2][4];
#pragma unroll
            for (int j = 0; j < 2; ++j) if (j < ntc3) {
                int nt = w + 16 * j;
                if (nt >= 13 && !(m & 1)) {
                    int c = (nt - 13) * 16 + m;
#pragma unroll
                    for (int i = 0; i < 4; ++i)
                        epv[j][i] = *(const h2*)(ep + ((size_t)(rb + q * 4 + i) * 64 + t) * 208 + c);
                }
            }
#pragma unroll
            for (int j = 0; j < 2; ++j) if (j < ntc3) {
                int nt = w + 16 * j;
                const _Float16* F = (nt < 13) ? Fimg : Fobsd;
                int ln = (nt < 13) ? nt : nt - 13;
                half8 b[7];
#pragma unroll
                for (int ks = 0; ks < 7; ++ks)
                    b[ks] = *(const half8*)(F + ((size_t)(ln * 7 + ks) * 64 + lane) * 8);
                f32x4 acc = {};
#pragma unroll
                for (int ks = 0; ks < 7; ++ks) {
                    half8 a = *(const half8*)(actG + m * 212 + 100 + ks * 16 + q * 4);
                    acc = MFMA16(a, b[ks], acc);
                }
                f32x4 accN;
#pragma unroll
                for (int i = 0; i < 4; ++i) accN[i] = __shfl_xor(acc[i], 1);
                if (!(m & 1)) {
                    int col = ln * 16 + m;
                    if (col < 200) {
                        if (nt < 13) {
#pragma unroll
                            for (int i = 0; i < 4; ++i)
                                actH[(q * 4 + i) * 116 + (col >> 1)] =
                                    packh2(elu_(acc[i] + bias[800 + col]),
                                           elu_(accN[i] + bias[800 + col + 1]));
                        } else {
#pragma unroll
                            for (int i = 0; i < 4; ++i)
                                actHO[(q * 4 + i) * 116 + (col >> 1)] =
                                    packh2(elu_(acc[i] + bias[1000 + col] + (float)epv[j][i][0]),
                                           elu_(accN[i] + bias[1000 + col + 1] + (float)epv[j][i][1]));
                        }
                    }
                }
            }
        }
        __syncthreads();  // D

        // ---- P4: stats preacts (reg-resident weights) -> parts cols 0..63 (ims), 64..127 (obs) ----
        if (w < 8) {
            const unsigned* Aact = (w < 4) ? actH : actHO;
            f32x4 acc = {};
#pragma unroll
            for (int ks = 0; ks < 7; ++ks) {
                half8 a = *(const half8*)(Aact + m * 116 + ks * 16 + q * 4);
                acc = MFMA16(a, bst[ks], acc);
            }
            int colbase = ((w < 4) ? 0 : 64) + (w & 3) * 16;
            _Float16* pw = parts + q * 4 * 616 + colbase + m;
#pragma unroll
            for (int i = 0; i < 4; ++i) pw[i * 616] = (_Float16)acc[i];
        }
        __syncthreads();  // E

        // ---- P5: mean/std/stoch + outputs; posterior stoch -> actI; action(t+1) pack ----
        if (tid < 480) {
            int side = p5_side, r = p5_r, cp = p5_cp;
            size_t ob = ((size_t)(rb + r) * 64 + t) * 380;
            int pbase = (side == 0) ? 0 : 64;
            int bb    = (side == 0) ? 1200 : 1260;
            h2 mh = *(const h2*)(parts + r * 616 + pbase + 2 * cp);
            h2 sh = *(const h2*)(parts + r * 616 + pbase + 30 + 2 * cp);
            float m0 = (float)mh[0] + bias[bb + 2 * cp];
            float m1 = (float)mh[1] + bias[bb + 2 * cp + 1];
            float s0 = sp_((float)sh[0] + bias[bb + 30 + 2 * cp]) + 0.1f;
            float s1 = sp_((float)sh[1] + bias[bb + 30 + 2 * cp + 1]) + 0.1f;
            float st0 = m0 + s0 * p5_nz.x, st1 = m1 + s1 * p5_nz.y;
            int o0 = (side == 0) ? 90 : 0;
            *(float2*)(out + ob + o0 + 2 * cp)      = make_float2(st0, st1);
            *(float2*)(out + ob + o0 + 30 + 2 * cp) = make_float2(m0, m1);
            *(float2*)(out + ob + o0 + 60 + 2 * cp) = make_float2(s0, s1);
            if (side == 1) actI[r * 36 + cp] = packh2(st0, st1);
        }
        if (tid < 96 && t < 63)
            actI[(tid / 6) * 36 + 15 + (tid % 6)] = packh2(p0_a2.x, p0_a2.y);
        __syncthreads();  // F
    }
}

extern "C" void kernel_launch(void* const* d_in, const int* in_sizes, int n_in,
                              void* d_out, int out_size, void* d_ws, size_t ws_size,
                              hipStream_t stream) {
    const float* embed   = (const float*)d_in[0];
    const float* action  = (const float*)d_in[1];
    const float* npr     = (const float*)d_in[2];
    const float* npo     = (const float*)d_in[3];
    const float* inpW    = (const float*)d_in[4];
    const float* inpb    = (const float*)d_in[5];
    const float* gruW    = (const float*)d_in[6];
    const float* grub    = (const float*)d_in[7];
    const float* imgW    = (const float*)d_in[8];
    const float* imgb    = (const float*)d_in[9];
    const float* imsW    = (const float*)d_in[10];
    const float* imsb    = (const float*)d_in[11];
    const float* obsoutW = (const float*)d_in[12];
    const float* obsoutb = (const float*)d_in[13];
    const float* obsW    = (const float*)d_in[14];
    const float* obsb    = (const float*)d_in[15];

    _Float16* ep    = (_Float16*)d_ws;
    _Float16* frags = (_Float16*)d_ws + EP_HALVES;

    prep_frags<<<1174, 64, 0, stream>>>(inpW, gruW, imgW, obsoutW, imsW, obsW, frags);
    ep_gemm<<<2048, 256, 0, stream>>>(embed, frags + (size_t)758 * 512, ep);
    rssm_scan<<<32, 1024, 0, stream>>>(action, npr, npo, inpb, grub, imgb, obsoutb,
                                       imsb, obsb, frags, ep, (float*)d_out);
}

// Round 3
// 1319.215 us; speedup vs baseline: 1.3946x; 1.3946x over previous
//
#include <hip/hip_runtime.h>

typedef _Float16 h2   __attribute__((ext_vector_type(2)));
typedef _Float16 h4   __attribute__((ext_vector_type(4)));
typedef _Float16 half8 __attribute__((ext_vector_type(8)));
typedef float f32x4   __attribute__((ext_vector_type(4)));

#define MFMA16(a,b,c) __builtin_amdgcn_mfma_f32_16x16x32_f16((a),(b),(c),0,0,0)

// B=512, T=64, STOCH=30, DETER=200, HIDDEN=200, A=12, EMBED=1024
// out row = [stoch_po(30), mean_po(30), std_po(30), stoch_pr(30), mean_pr(30), std_pr(30), deter(200)] = 380

// Fragment regions (1KB blocks = 64 lanes x 8 halves), B-frag order [nt][ks][lane][8]
// INP: NT=13 KS=2 @0(26) | GRU: NT=38 KS=13 @26(494) | IMG: NT=13 KS=7 @520(91)
// OBSD: NT=13 KS=7 @611(91) | IMS: NT=4 KS=7 @702(28) | OBS: NT=4 KS=7 @730(28)
// W2: NT=13 KS=32 @758(416) -> 1174 blocks
#define EP_HALVES ((size_t)32768*208)

__global__ void prep_frags(const float* __restrict__ inpW, const float* __restrict__ gruW,
                           const float* __restrict__ imgW, const float* __restrict__ obsoutW,
                           const float* __restrict__ imsW, const float* __restrict__ obsW,
                           _Float16* __restrict__ frags) {
    int gb = blockIdx.x, lane = threadIdx.x;
    const float* src; int KS, K, N, ld, roff = 0, local;
    if (gb < 26)       { src = inpW;    KS = 2;  K = 42;   N = 200; ld = 200; local = gb; }
    else if (gb < 520) { src = gruW;    KS = 13; K = 400;  N = 600; ld = 600; local = gb - 26; }
    else if (gb < 611) { src = imgW;    KS = 7;  K = 200;  N = 200; ld = 200; local = gb - 520; }
    else if (gb < 702) { src = obsoutW; KS = 7;  K = 200;  N = 200; ld = 200; local = gb - 611; }
    else if (gb < 730) { src = imsW;    KS = 7;  K = 200;  N = 60;  ld = 60;  local = gb - 702; }
    else if (gb < 758) { src = obsW;    KS = 7;  K = 200;  N = 60;  ld = 60;  local = gb - 730; }
    else               { src = obsoutW; KS = 32; K = 1024; N = 200; ld = 200; roff = 200; local = gb - 758; }
    int nt = local / KS, ks = local % KS;
    int n  = nt * 16 + (lane & 15);
    int k0 = ks * 32 + (lane >> 4) * 8;
    half8 v;
#pragma unroll
    for (int j = 0; j < 8; ++j) {
        int k = k0 + j;
        float f = (k < K && n < N) ? src[(size_t)(k + roff) * ld + n] : 0.0f;
        v[j] = (_Float16)f;
    }
    *(half8*)(frags + (size_t)gb * 512 + lane * 8) = v;
}

__global__ __launch_bounds__(256) void ep_gemm(const float* __restrict__ embed,
                                               const _Float16* __restrict__ w2f,
                                               _Float16* __restrict__ ep) {
    __shared__ __align__(16) _Float16 aE[16 * 1048];
    int tid = threadIdx.x;
    int rb = blockIdx.x * 16;
    for (int i = 0; i < 16; ++i) {
        float4 e = *((const float4*)(embed + (size_t)(rb + i) * 1024) + tid);
        h4 hv; hv[0] = (_Float16)e.x; hv[1] = (_Float16)e.y; hv[2] = (_Float16)e.z; hv[3] = (_Float16)e.w;
        *(h4*)(aE + i * 1048 + tid * 4) = hv;
    }
    __syncthreads();
    int w = tid >> 6, lane = tid & 63, m = lane & 15, q = lane >> 4;
    f32x4 acc[4] = {};
    int nts[4]; int ntc = 0;
    for (int nt = w; nt < 13; nt += 4) nts[ntc++] = nt;
    for (int ks = 0; ks < 32; ++ks) {
        half8 a = *(const half8*)(aE + m * 1048 + ks * 32 + q * 8);
#pragma unroll
        for (int j = 0; j < 4; ++j) if (j < ntc) {
            half8 b = *(const half8*)(w2f + ((size_t)(nts[j] * 32 + ks) * 64 + lane) * 8);
            acc[j] = MFMA16(a, b, acc[j]);
        }
    }
    for (int j = 0; j < ntc; ++j) {
        int col = nts[j] * 16 + m;
#pragma unroll
        for (int i = 0; i < 4; ++i)
            ep[(size_t)(rb + q * 4 + i) * 208 + col] = (_Float16)acc[j][i];
    }
}

__device__ __forceinline__ float sigm_(float x) { return 1.0f / (1.0f + __expf(-x)); }
__device__ __forceinline__ float tanh_(float x) { float e = __expf(2.0f * x); return 1.0f - 2.0f / (e + 1.0f); }
__device__ __forceinline__ float elu_(float x)  { return x > 0.0f ? x : __expf(x) - 1.0f; }
__device__ __forceinline__ float sp_(float x)   { return fmaxf(x, 0.0f) + log1pf(__expf(-fabsf(x))); }
__device__ __forceinline__ unsigned packh2(float a, float b) {
    h2 p; p[0] = (_Float16)a; p[1] = (_Float16)b;
    return __builtin_bit_cast(unsigned, p);
}

// Pair design: group g (16 rows) handled by WG g (side 0, img/prior) + WG g+32 (side 1, obs/post).
// All weights register-resident. Per step exactly 2 cross-WG syncs:
//   B: parts(t) ready (both sides wrote their 19 GRU tiles)
//   D: stoch(t)/gates-consumption done (side1 wrote stochbuf; both sides done reading parts)
// Hazard proofs:
//   parts(t+1) writes happen after wait-D(t) [other side posted D after its last parts(t) read in gates] -> safe.
//   stochbuf(t+1) written by side1 after wait-B(t+1) [side0 posted B(t+1) after P2(t+1), which is after
//     its P1(t+1) read of stochbuf(t)] -> safe.
__global__ __launch_bounds__(1024) void rssm_scan(
    const float* __restrict__ action, const float* __restrict__ npr, const float* __restrict__ npo,
    const float* __restrict__ inp_b, const float* __restrict__ gru_b,
    const float* __restrict__ img_b, const float* __restrict__ obsout_b,
    const float* __restrict__ ims_b, const float* __restrict__ obs_b,
    const _Float16* __restrict__ frags, const _Float16* __restrict__ ep,
    _Float16* __restrict__ partsbuf, unsigned* __restrict__ stochbuf,
    int* __restrict__ flags, float* __restrict__ out) {

    __shared__ __align__(16) unsigned actI[16 * 36];    // [stoch(15p) action(6p) zeropad]
    __shared__ __align__(16) unsigned actG[16 * 212];   // [x(100p) deter(100p) zeropad]
    __shared__ __align__(16) unsigned actX[16 * 116];   // h (side0) / ho (side1)
    __shared__ float statspre[16 * 65];                 // raw stats preacts (+1 pad)
    __shared__ float bias[1320];  // inp200 | gru600 | img200 | obsout200 | ims60 | obs60

    const _Float16* Finp  = frags;
    const _Float16* Fgru  = frags + (size_t)26  * 512;
    const _Float16* Fimg  = frags + (size_t)520 * 512;
    const _Float16* Fobsd = frags + (size_t)611 * 512;
    const _Float16* Fims  = frags + (size_t)702 * 512;
    const _Float16* Fobs  = frags + (size_t)730 * 512;

    const int tid = threadIdx.x, w = tid >> 6, lane = tid & 63, m = lane & 15, q = lane >> 4;
    const int g = blockIdx.x & 31, side = blockIdx.x >> 5;
    const int rb = g * 16;
    _Float16* gparts = partsbuf + (size_t)g * (16 * 608);
    unsigned* gstoch = stochbuf + (size_t)g * (16 * 16);
    int* gflags = flags + g * 256;   // [t][sync][side]

    for (int i = tid; i < 1320; i += 1024) {
        float v;
        if (i < 200) v = inp_b[i];
        else if (i < 800)  v = gru_b[i - 200];
        else if (i < 1000) v = img_b[i - 800];
        else if (i < 1200) v = obsout_b[i - 1000];
        else if (i < 1260) v = ims_b[i - 1200];
        else               v = obs_b[i - 1260];
        bias[i] = v;
    }
    for (int i = tid; i < 16 * 36;  i += 1024) actI[i] = 0u;
    for (int i = tid; i < 16 * 212; i += 1024) actG[i] = 0u;
    for (int i = tid; i < 16 * 116; i += 1024) actX[i] = 0u;

    // ---- persistent register weights ----
    half8 binp[2];                        // INP tile w (redundant both sides), w<13
    {
        int wt = (w < 13) ? w : 0;
#pragma unroll
        for (int ks = 0; ks < 2; ++ks)
            binp[ks] = *(const half8*)(Finp + ((size_t)(wt * 2 + ks) * 64 + lane) * 8);
    }
    half8 bg0[13], bg1[13];               // GRU tiles side*19 + w, side*19+16+w (w<3)
    {
        int t0 = side * 19 + w;           // 0..34, always valid
        int t1 = side * 19 + 16 + ((w < 3) ? w : 0);
#pragma unroll
        for (int ks = 0; ks < 13; ++ks) {
            bg0[ks] = *(const half8*)(Fgru + ((size_t)(t0 * 13 + ks) * 64 + lane) * 8);
            bg1[ks] = *(const half8*)(Fgru + ((size_t)(t1 * 13 + ks) * 64 + lane) * 8);
        }
    }
    half8 bp3[7];                         // side0: IMG tile w ; side1: OBSD tile w (w<13)
    {
        const _Float16* F = side ? Fobsd : Fimg;
        int wt = (w < 13) ? w : 0;
#pragma unroll
        for (int ks = 0; ks < 7; ++ks)
            bp3[ks] = *(const half8*)(F + ((size_t)(wt * 7 + ks) * 64 + lane) * 8);
    }
    half8 bp4[7];                         // side0: IMS tile w ; side1: OBS tile w (w<4)
    {
        const _Float16* F = side ? Fobs : Fims;
        int wt = (w < 4) ? w : 0;
#pragma unroll
        for (int ks = 0; ks < 7; ++ks)
            bp4[ks] = *(const half8*)(F + ((size_t)(wt * 7 + ks) * 64 + lane) * 8);
    }

    auto post_flag = [&](int t, int sync, int val) {
        // caller guarantees a __syncthreads() already drained all waves' stores
        if (tid == 0)
            __hip_atomic_store(&gflags[t * 4 + sync * 2 + side], val,
                               __ATOMIC_RELEASE, __HIP_MEMORY_SCOPE_AGENT);
    };
    auto wait_flag = [&](int t, int sync, int val) {
        if (tid == 0) {
            int* f = &gflags[t * 4 + sync * 2 + (1 - side)];
            int it = 0;
            while (__hip_atomic_load(f, __ATOMIC_ACQUIRE, __HIP_MEMORY_SCOPE_AGENT) != val) {
                __builtin_amdgcn_s_sleep(1);
                if (++it > (1 << 20)) break;   // fail to wrong-answer, not hang
            }
        }
        __syncthreads();
    };

    auto phase_P1pack = [&](int t, bool readStoch) {
        if (readStoch && tid < 240) {
            int r = tid / 15, cp = tid % 15;
            actI[r * 36 + cp] = gstoch[r * 16 + cp];
        }
        if (tid < 96) {
            int r = tid / 6, cp = tid % 6;
            float2 a2 = *(const float2*)(action + ((size_t)(rb + r) * 64 + t) * 12 + 2 * cp);
            actI[r * 36 + 15 + cp] = packh2(a2.x, a2.y);
        }
    };
    auto phase_P1mfma = [&]() {
        if (w < 13) {
            f32x4 acc = {};
#pragma unroll
            for (int ks = 0; ks < 2; ++ks) {
                half8 a = *(const half8*)(actI + m * 36 + ks * 16 + q * 4);
                acc = MFMA16(a, binp[ks], acc);
            }
            f32x4 accN;
#pragma unroll
            for (int i = 0; i < 4; ++i) accN[i] = __shfl_xor(acc[i], 1);
            if (!(m & 1)) {
                int col = w * 16 + m;
                if (col < 200) {
#pragma unroll
                    for (int i = 0; i < 4; ++i)
                        actG[(q * 4 + i) * 212 + (col >> 1)] =
                            packh2(elu_(acc[i] + bias[col]), elu_(accN[i] + bias[col + 1]));
                }
            }
        }
    };
    auto phase_P2 = [&]() {
        f32x4 a0 = {}, a1 = {};
#pragma unroll
        for (int ks = 0; ks < 13; ++ks) {
            half8 a = *(const half8*)(actG + m * 212 + ks * 16 + q * 4);
            a0 = MFMA16(a, bg0[ks], a0);
            if (w < 3) a1 = MFMA16(a, bg1[ks], a1);
        }
        int c0 = (side * 19 + w) * 16 + m;
        _Float16* p0 = gparts + q * 4 * 608 + c0;
#pragma unroll
        for (int i = 0; i < 4; ++i) p0[i * 608] = (_Float16)a0[i];
        if (w < 3) {
            int c1 = (side * 19 + 16 + w) * 16 + m;
            _Float16* p1 = gparts + q * 4 * 608 + c1;
#pragma unroll
            for (int i = 0; i < 4; ++i) p1[i * 608] = (_Float16)a1[i];
        }
    };
    auto phase_gates = [&](int t) {
        for (int idx = tid; idx < 1600; idx += 1024) {
            int r = idx / 100, cp = idx % 100;
            const _Float16* pr = gparts + r * 608;
            h2 p0 = *(const h2*)(pr + 2 * cp);
            h2 p1 = *(const h2*)(pr + 200 + 2 * cp);
            h2 p2 = *(const h2*)(pr + 400 + 2 * cp);
            h2 dold = *(const h2*)&actG[r * 212 + 100 + cp];
            float dn[2];
#pragma unroll
            for (int e = 0; e < 2; ++e) {
                int n = 2 * cp + e;
                float reset = sigm_((float)p0[e] + bias[200 + n]);
                float cand  = tanh_(reset * ((float)p1[e] + bias[400 + n]));
                float upd   = sigm_((float)p2[e] + bias[600 + n] - 1.0f);
                dn[e] = upd * cand + (1.0f - upd) * (float)dold[e];
            }
            actG[r * 212 + 100 + cp] = packh2(dn[0], dn[1]);
            bool mine = side ? (cp >= 50) : (cp < 50);
            if (mine)
                *(float2*)(out + ((size_t)(rb + r) * 64 + t) * 380 + 180 + 2 * cp) = make_float2(dn[0], dn[1]);
        }
    };
    auto phase_P3 = [&](int t) {
        if (w < 13) {
            int col = w * 16 + m;
            h2 epv[4];
            if (side == 1 && !(m & 1) && col < 200) {
#pragma unroll
                for (int i = 0; i < 4; ++i)
                    epv[i] = *(const h2*)(ep + ((size_t)(rb + q * 4 + i) * 64 + t) * 208 + col);
            }
            f32x4 acc = {};
#pragma unroll
            for (int ks = 0; ks < 7; ++ks) {
                half8 a = *(const half8*)(actG + m * 212 + 100 + ks * 16 + q * 4);
                acc = MFMA16(a, bp3[ks], acc);
            }
            f32x4 accN;
#pragma unroll
            for (int i = 0; i < 4; ++i) accN[i] = __shfl_xor(acc[i], 1);
            if (!(m & 1) && col < 200) {
                if (side == 0) {
#pragma unroll
                    for (int i = 0; i < 4; ++i)
                        actX[(q * 4 + i) * 116 + (col >> 1)] =
                            packh2(elu_(acc[i] + bias[800 + col]),
                                   elu_(accN[i] + bias[800 + col + 1]));
                } else {
#pragma unroll
                    for (int i = 0; i < 4; ++i)
                        actX[(q * 4 + i) * 116 + (col >> 1)] =
                            packh2(elu_(acc[i] + bias[1000 + col] + (float)epv[i][0]),
                                   elu_(accN[i] + bias[1000 + col + 1] + (float)epv[i][1]));
                }
            }
        }
    };
    auto phase_P4 = [&]() {
        if (w < 4) {
            f32x4 acc = {};
#pragma unroll
            for (int ks = 0; ks < 7; ++ks) {
                half8 a = *(const half8*)(actX + m * 116 + ks * 16 + q * 4);
                acc = MFMA16(a, bp4[ks], acc);
            }
#pragma unroll
            for (int i = 0; i < 4; ++i)
                statspre[(q * 4 + i) * 65 + w * 16 + m] = acc[i];
        }
    };
    auto phase_P5 = [&](int t) {
        if (tid < 240) {
            int r = tid / 15, cp = tid % 15;
            int bb = side ? 1260 : 1200;
            float m0 = statspre[r * 65 + 2 * cp]     + bias[bb + 2 * cp];
            float m1 = statspre[r * 65 + 2 * cp + 1] + bias[bb + 2 * cp + 1];
            float s0 = sp_(statspre[r * 65 + 30 + 2 * cp]     + bias[bb + 30 + 2 * cp]) + 0.1f;
            float s1 = sp_(statspre[r * 65 + 30 + 2 * cp + 1] + bias[bb + 30 + 2 * cp + 1]) + 0.1f;
            const float* ns = side ? npo : npr;
            float2 nz = *(const float2*)(ns + ((size_t)(rb + r) * 64 + t) * 30 + 2 * cp);
            float st0 = m0 + s0 * nz.x, st1 = m1 + s1 * nz.y;
            size_t ob = ((size_t)(rb + r) * 64 + t) * 380;
            int o0 = side ? 0 : 90;
            *(float2*)(out + ob + o0 + 2 * cp)      = make_float2(st0, st1);
            *(float2*)(out + ob + o0 + 30 + 2 * cp) = make_float2(m0, m1);
            *(float2*)(out + ob + o0 + 60 + 2 * cp) = make_float2(s0, s1);
            if (side == 1) gstoch[r * 16 + cp] = packh2(st0, st1);
        }
    };

    __syncthreads();
    // bootstrap t=0: stoch=0 (zero-init), deter=0
    phase_P1pack(0, false);
    __syncthreads();
    phase_P1mfma();
    __syncthreads();
    phase_P2();
    __syncthreads();          // drains all waves' gparts stores
    post_flag(0, 0, 1);       // B(0)

    for (int t = 0; t < 64; ++t) {
        wait_flag(t, 0, t + 1);       // B(t): partner's parts ready
        phase_gates(t);
        __syncthreads();
        phase_P3(t);
        __syncthreads();
        phase_P4();
        __syncthreads();
        phase_P5(t);
        if (t == 63) break;
        __syncthreads();              // drains P5 stores (gstoch, outs)
        post_flag(t, 1, t + 1);       // D(t)
        wait_flag(t, 1, t + 1);       // partner done consuming parts(t), stoch ready
        phase_P1pack(t + 1, true);
        __syncthreads();
        phase_P1mfma();
        __syncthreads();
        phase_P2();
        __syncthreads();              // drains gparts stores
        post_flag(t + 1, 0, t + 2);   // B(t+1)
    }
}

extern "C" void kernel_launch(void* const* d_in, const int* in_sizes, int n_in,
                              void* d_out, int out_size, void* d_ws, size_t ws_size,
                              hipStream_t stream) {
    const float* embed   = (const float*)d_in[0];
    const float* action  = (const float*)d_in[1];
    const float* npr     = (const float*)d_in[2];
    const float* npo     = (const float*)d_in[3];
    const float* inpW    = (const float*)d_in[4];
    const float* inpb    = (const float*)d_in[5];
    const float* gruW    = (const float*)d_in[6];
    const float* grub    = (const float*)d_in[7];
    const float* imgW    = (const float*)d_in[8];
    const float* imgb    = (const float*)d_in[9];
    const float* imsW    = (const float*)d_in[10];
    const float* imsb    = (const float*)d_in[11];
    const float* obsoutW = (const float*)d_in[12];
    const float* obsoutb = (const float*)d_in[13];
    const float* obsW    = (const float*)d_in[14];
    const float* obsb    = (const float*)d_in[15];

    char* ws = (char*)d_ws;
    _Float16* ep     = (_Float16*)ws;                              // 13,631,488 B
    _Float16* frags  = (_Float16*)(ws + EP_HALVES * 2);            // 1,202,176 B
    char* p          = ws + EP_HALVES * 2 + (size_t)1174 * 1024;
    _Float16* partsb = (_Float16*)p;                               // 32*16*608*2 = 622,592 B
    p += (size_t)32 * 16 * 608 * 2;
    unsigned* stochb = (unsigned*)p;                               // 32*16*16*4 = 32,768 B
    p += (size_t)32 * 16 * 16 * 4;
    int* flags       = (int*)p;                                    // 32*256*4 = 32,768 B

    prep_frags<<<1174, 64, 0, stream>>>(inpW, gruW, imgW, obsoutW, imsW, obsW, frags);
    ep_gemm<<<2048, 256, 0, stream>>>(embed, frags + (size_t)758 * 512, ep);
    rssm_scan<<<64, 1024, 0, stream>>>(action, npr, npo, inpb, grub, imgb, obsoutb,
                                       imsb, obsb, frags, ep, partsb, stochb, flags,
                                       (float*)d_out);
}

// Round 4
// 997.707 us; speedup vs baseline: 1.8440x; 1.3222x over previous
//
#include <hip/hip_runtime.h>

typedef _Float16 h2   __attribute__((ext_vector_type(2)));
typedef _Float16 h4   __attribute__((ext_vector_type(4)));
typedef _Float16 half8 __attribute__((ext_vector_type(8)));
typedef float f32x4   __attribute__((ext_vector_type(4)));

#define MFMA16(a,b,c) __builtin_amdgcn_mfma_f32_16x16x32_f16((a),(b),(c),0,0,0)
#define ATOMIC_ST(p,v) __hip_atomic_store((p),(v),__ATOMIC_RELAXED,__HIP_MEMORY_SCOPE_AGENT)
#define ATOMIC_LD(p)   __hip_atomic_load((p),__ATOMIC_RELAXED,__HIP_MEMORY_SCOPE_AGENT)

// B=512, T=64, STOCH=30, DETER=200, HIDDEN=200, A=12, EMBED=1024
// out row = [stoch_po(30), mean_po(30), std_po(30), stoch_pr(30), mean_pr(30), std_pr(30), deter(200)] = 380

// Fragment regions (1KB blocks = 64 lanes x 8 halves), B-frag order [nt][ks][lane][8]
// INP: NT=13 KS=2 @0(26) | GRU: NT=38 KS=13 @26(494) | IMG: NT=13 KS=7 @520(91)
// OBSD: NT=13 KS=7 @611(91) | IMS: NT=4 KS=7 @702(28) | OBS: NT=4 KS=7 @730(28)
// W2: NT=13 KS=32 @758(416) -> 1174 blocks
#define EP_HALVES ((size_t)32768*208)

__global__ void prep_frags(const float* __restrict__ inpW, const float* __restrict__ gruW,
                           const float* __restrict__ imgW, const float* __restrict__ obsoutW,
                           const float* __restrict__ imsW, const float* __restrict__ obsW,
                           _Float16* __restrict__ frags) {
    int gb = blockIdx.x, lane = threadIdx.x;
    const float* src; int KS, K, N, ld, roff = 0, local;
    if (gb < 26)       { src = inpW;    KS = 2;  K = 42;   N = 200; ld = 200; local = gb; }
    else if (gb < 520) { src = gruW;    KS = 13; K = 400;  N = 600; ld = 600; local = gb - 26; }
    else if (gb < 611) { src = imgW;    KS = 7;  K = 200;  N = 200; ld = 200; local = gb - 520; }
    else if (gb < 702) { src = obsoutW; KS = 7;  K = 200;  N = 200; ld = 200; local = gb - 611; }
    else if (gb < 730) { src = imsW;    KS = 7;  K = 200;  N = 60;  ld = 60;  local = gb - 702; }
    else if (gb < 758) { src = obsW;    KS = 7;  K = 200;  N = 60;  ld = 60;  local = gb - 730; }
    else               { src = obsoutW; KS = 32; K = 1024; N = 200; ld = 200; roff = 200; local = gb - 758; }
    int nt = local / KS, ks = local % KS;
    int n  = nt * 16 + (lane & 15);
    int k0 = ks * 32 + (lane >> 4) * 8;
    half8 v;
#pragma unroll
    for (int j = 0; j < 8; ++j) {
        int k = k0 + j;
        float f = (k < K && n < N) ? src[(size_t)(k + roff) * ld + n] : 0.0f;
        v[j] = (_Float16)f;
    }
    *(half8*)(frags + (size_t)gb * 512 + lane * 8) = v;
}

// ep[row][0..207] = embed[row] @ obs_out_W[200:,:]  (f16), row = b*64+t
// double-buffered B over ks to hide L2 latency
__global__ __launch_bounds__(256) void ep_gemm(const float* __restrict__ embed,
                                               const _Float16* __restrict__ w2f,
                                               _Float16* __restrict__ ep) {
    __shared__ __align__(16) _Float16 aE[16 * 1048];
    int tid = threadIdx.x;
    int rb = blockIdx.x * 16;
#pragma unroll
    for (int i = 0; i < 16; ++i) {
        float4 e = *((const float4*)(embed + (size_t)(rb + i) * 1024) + tid);
        h4 hv; hv[0] = (_Float16)e.x; hv[1] = (_Float16)e.y; hv[2] = (_Float16)e.z; hv[3] = (_Float16)e.w;
        *(h4*)(aE + i * 1048 + tid * 4) = hv;
    }
    __syncthreads();
    int w = tid >> 6, lane = tid & 63, m = lane & 15, q = lane >> 4;
    f32x4 acc[4] = {};
    int nts[4]; int ntc = 0;
    for (int nt = w; nt < 13; nt += 4) nts[ntc++] = nt;
    half8 bb[2][4];
#pragma unroll
    for (int j = 0; j < 4; ++j) if (j < ntc)
        bb[0][j] = *(const half8*)(w2f + ((size_t)(nts[j] * 32) * 64 + lane) * 8);
#pragma unroll
    for (int ks = 0; ks < 32; ++ks) {
        int cur = ks & 1, nxt = cur ^ 1;
        if (ks < 31) {
#pragma unroll
            for (int j = 0; j < 4; ++j) if (j < ntc)
                bb[nxt][j] = *(const half8*)(w2f + ((size_t)(nts[j] * 32 + ks + 1) * 64 + lane) * 8);
        }
        half8 a = *(const half8*)(aE + m * 1048 + ks * 32 + q * 8);
#pragma unroll
        for (int j = 0; j < 4; ++j) if (j < ntc)
            acc[j] = MFMA16(a, bb[cur][j], acc[j]);
    }
    for (int j = 0; j < ntc; ++j) {
        int col = nts[j] * 16 + m;
#pragma unroll
        for (int i = 0; i < 4; ++i)
            ep[(size_t)(rb + q * 4 + i) * 208 + col] = (_Float16)acc[j][i];
    }
}

__device__ __forceinline__ float sigm_(float x) { return 1.0f / (1.0f + __expf(-x)); }
__device__ __forceinline__ float tanh_(float x) { float e = __expf(2.0f * x); return 1.0f - 2.0f / (e + 1.0f); }
__device__ __forceinline__ float elu_(float x)  { return x > 0.0f ? x : __expf(x) - 1.0f; }
__device__ __forceinline__ float sp_(float x)   { return fmaxf(x, 0.0f) + log1pf(__expf(-fabsf(x))); }
__device__ __forceinline__ unsigned packh2(float a, float b) {
    h2 p; p[0] = (_Float16)a; p[1] = (_Float16)b;
    return __builtin_bit_cast(unsigned, p);
}

// Quad design: group g = 16 rows, WGs wg=0..3 (blockIdx = wg*32+g).
//   wg quarter: deter dims n in [50*wg, 50*wg+50)
//   GRU tiles per wg (12): gate0 {3wg..3wg+3}, gate1 {12+3wg..+3}, gate2 {25+3wg..+3}
//     -> gates(n-range) reads ONLY local parts (LDS). Cross-WG traffic per step:
//        deter quarter (16x25 dw out, 75 in) + stoch (16x15 dw, wg2->others), via
//        relaxed agent atomics (coherent instructions, NO fences -> no L2 flushes).
//   Ordering: data atomics complete (vmcnt0) at the __syncthreads before each flag post.
//   Double-buffer (t parity) qdet/stochb; reader(t)'s read precedes its later flag posts,
//   which gate the writer's arrival at t+2 (chain via S1/S2 waits) -> no overwrite race.
//   wg0: P3(IMG)+P4(IMS)+P5 prior outs; wg2: P3(OBSD+ep)+P4(OBS)+P5 post outs + stoch publish;
//   wg1/wg3: only GRU quarter + gates; idle through P3-P5.
__global__ __launch_bounds__(512, 2) void rssm_scan(
    const float* __restrict__ action, const float* __restrict__ npr, const float* __restrict__ npo,
    const float* __restrict__ inp_b, const float* __restrict__ gru_b,
    const float* __restrict__ img_b, const float* __restrict__ obsout_b,
    const float* __restrict__ ims_b, const float* __restrict__ obs_b,
    const _Float16* __restrict__ frags, const _Float16* __restrict__ ep,
    unsigned* __restrict__ qdet, unsigned* __restrict__ stochb,
    unsigned* __restrict__ flags, float* __restrict__ out) {

    __shared__ __align__(16) unsigned actI[16 * 36];    // [stoch(15p) action(6p) zeropad]
    __shared__ __align__(16) unsigned actG[16 * 212];   // [x(100p) deter(100p) zeropad]
    __shared__ __align__(16) unsigned actX[16 * 116];   // h (wg0) / ho (wg2)
    __shared__ __align__(16) _Float16 parts[16 * 208];  // local 12 GRU tiles (f16)
    __shared__ float statspre[16 * 65];
    __shared__ float bias[1320];  // inp200 | gru600 | img200 | obsout200 | ims60 | obs60

    const _Float16* Finp  = frags;
    const _Float16* Fgru  = frags + (size_t)26  * 512;
    const _Float16* Fimg  = frags + (size_t)520 * 512;
    const _Float16* Fobsd = frags + (size_t)611 * 512;
    const _Float16* Fims  = frags + (size_t)702 * 512;
    const _Float16* Fobs  = frags + (size_t)730 * 512;

    const int tid = threadIdx.x, w = tid >> 6, lane = tid & 63, m = lane & 15, q = lane >> 4;
    const int g = blockIdx.x & 31, wg = blockIdx.x >> 5;
    const int rb = g * 16;
    const bool post = (wg >= 2);
    const bool statside = (wg == 0) || (wg == 2);
    unsigned* gf = flags + g * 512;   // [t(64)][slot(8)]: 0..3 deter per wg, 4 stoch

    for (int i = tid; i < 1320; i += 512) {
        float v;
        if (i < 200) v = inp_b[i];
        else if (i < 800)  v = gru_b[i - 200];
        else if (i < 1000) v = img_b[i - 800];
        else if (i < 1200) v = obsout_b[i - 1000];
        else if (i < 1260) v = ims_b[i - 1200];
        else               v = obs_b[i - 1260];
        bias[i] = v;
    }
    for (int i = tid; i < 16 * 36;  i += 512) actI[i] = 0u;
    for (int i = tid; i < 16 * 212; i += 512) actG[i] = 0u;
    for (int i = tid; i < 16 * 116; i += 512) actX[i] = 0u;

    // ---- persistent register weights (static ~ (13+13+7+7)*4 = 160 VGPR + working) ----
    half8 bgru0[13];  // GRU tile A: w<4 -> gate0 tile 3wg+w ; w>=4 -> gate1 tile 12+3wg+(w-4)
    {
        int tA = (w < 4) ? (3 * wg + w) : (12 + 3 * wg + (w - 4));
#pragma unroll
        for (int ks = 0; ks < 13; ++ks)
            bgru0[ks] = *(const half8*)(Fgru + ((size_t)(tA * 13 + ks) * 64 + lane) * 8);
    }
    half8 bgru1[13];  // w<4: gate2 tile 25+3wg+w
    if (w < 4) {
        int tB = 25 + 3 * wg + w;
#pragma unroll
        for (int ks = 0; ks < 13; ++ks)
            bgru1[ks] = *(const half8*)(Fgru + ((size_t)(tB * 13 + ks) * 64 + lane) * 8);
    }
    const _Float16* F3 = post ? Fobsd : Fimg;
    const _Float16* F4 = post ? Fobs : Fims;
    half8 bp3a[7];    // P3 tile w (0..7)
    if (statside) {
#pragma unroll
        for (int ks = 0; ks < 7; ++ks)
            bp3a[ks] = *(const half8*)(F3 + ((size_t)(w * 7 + ks) * 64 + lane) * 8);
    }
    half8 bp4[7];     // w in 4..7: stats tile w-4
    if (statside && w >= 4) {
#pragma unroll
        for (int ks = 0; ks < 7; ++ks)
            bp4[ks] = *(const half8*)(F4 + ((size_t)((w - 4) * 7 + ks) * 64 + lane) * 8);
    }
    __syncthreads();

    for (int t = 0; t < 64; ++t) {
        // ---- top: S2 wait + stoch load (wg != 2, t>0); action pack; noise prefetch ----
        if (t > 0 && wg != 2) {
            if (tid == 0) {
                unsigned* f = gf + (t - 1) * 8 + 4;
                int it = 0;
                while (ATOMIC_LD(f) != (unsigned)t) {
                    __builtin_amdgcn_s_sleep(1);
                    if (++it > (1 << 20)) break;
                }
            }
            __syncthreads();
            __atomic_signal_fence(__ATOMIC_ACQUIRE);
            if (tid < 240) {
                int r = tid / 15, cp = tid % 15;
                actI[r * 36 + cp] =
                    ATOMIC_LD(stochb + (size_t)((((t - 1) & 1) * 32 + g)) * 256 + r * 16 + cp);
            }
        }
        if (tid < 96) {
            int r = tid / 6, cp = tid % 6;
            float2 a2 = *(const float2*)(action + ((size_t)(rb + r) * 64 + t) * 12 + 2 * cp);
            actI[r * 36 + 15 + cp] = packh2(a2.x, a2.y);
        }
        float2 nz = make_float2(0.0f, 0.0f);
        if (statside && tid < 240) {
            int r = tid / 15, cp = tid % 15;
            const float* ns = post ? npo : npr;
            nz = *(const float2*)(ns + ((size_t)(rb + r) * 64 + t) * 30 + 2 * cp);
        }
        __syncthreads();

        // ---- P1: x = elu(cat(stoch,action)@inp_W + b) -> actG[0..99] (INP streamed from L2) ----
        {
            half8 bi0[2], bi1[2];
#pragma unroll
            for (int ks = 0; ks < 2; ++ks)
                bi0[ks] = *(const half8*)(Finp + ((size_t)(w * 2 + ks) * 64 + lane) * 8);
            if (w < 5) {
#pragma unroll
                for (int ks = 0; ks < 2; ++ks)
                    bi1[ks] = *(const half8*)(Finp + ((size_t)((8 + w) * 2 + ks) * 64 + lane) * 8);
            }
            f32x4 acc = {}, acc2 = {};
#pragma unroll
            for (int ks = 0; ks < 2; ++ks) {
                half8 a = *(const half8*)(actI + m * 36 + ks * 16 + q * 4);
                acc = MFMA16(a, bi0[ks], acc);
                if (w < 5) acc2 = MFMA16(a, bi1[ks], acc2);
            }
            f32x4 accN;
#pragma unroll
            for (int i = 0; i < 4; ++i) accN[i] = __shfl_xor(acc[i], 1);
            if (!(m & 1)) {
                int col = w * 16 + m;   // <= 127 < 200
#pragma unroll
                for (int i = 0; i < 4; ++i)
                    actG[(q * 4 + i) * 212 + (col >> 1)] =
                        packh2(elu_(acc[i] + bias[col]), elu_(accN[i] + bias[col + 1]));
            }
            if (w < 5) {
                f32x4 acc2N;
#pragma unroll
                for (int i = 0; i < 4; ++i) acc2N[i] = __shfl_xor(acc2[i], 1);
                if (!(m & 1)) {
                    int col = (8 + w) * 16 + m;
                    if (col < 200) {
#pragma unroll
                        for (int i = 0; i < 4; ++i)
                            actG[(q * 4 + i) * 212 + (col >> 1)] =
                                packh2(elu_(acc2[i] + bias[col]), elu_(acc2N[i] + bias[col + 1]));
                    }
                }
            }
        }
        __syncthreads();

        // ---- P2: local 12 GRU tiles -> parts (LDS) ----
        {
            f32x4 a0 = {}, a1 = {};
#pragma unroll
            for (int ks = 0; ks < 13; ++ks) {
                half8 a = *(const half8*)(actG + m * 212 + ks * 16 + q * 4);
                a0 = MFMA16(a, bgru0[ks], a0);
                if (w < 4) a1 = MFMA16(a, bgru1[ks], a1);
            }
#pragma unroll
            for (int i = 0; i < 4; ++i)
                parts[(q * 4 + i) * 208 + w * 16 + m] = (_Float16)a0[i];
            if (w < 4) {
#pragma unroll
                for (int i = 0; i < 4; ++i)
                    parts[(q * 4 + i) * 208 + (8 + w) * 16 + m] = (_Float16)a1[i];
            }
        }
        // prefetch P3 tile 8+w (consumed after S1; drains behind gates/S1)
        half8 pf3[7];
        if (statside && w < 5) {
#pragma unroll
            for (int ks = 0; ks < 7; ++ks)
                pf3[ks] = *(const half8*)(F3 + ((size_t)((8 + w) * 7 + ks) * 64 + lane) * 8);
        }
        __syncthreads();

        // ---- gates: own n-quarter -> deter_new (local actG + coherent qdet + out) ----
        unsigned* qd = qdet + (size_t)((t & 1) * 32 + g) * 1600;
        if (tid < 400) {
            int r = tid / 25, p = tid % 25;
            int n0 = 50 * wg + 2 * p;
            float pg[3][2];
#pragma unroll
            for (int j = 0; j < 3; ++j) {
                int cg = n0 + 200 * j;
                int bj = (j == 0) ? 3 * wg : (j == 1) ? 12 + 3 * wg : 25 + 3 * wg;
                int lt = 4 * j + (cg >> 4) - bj;
                h2 v = *(const h2*)(parts + r * 208 + lt * 16 + (cg & 15));
                pg[j][0] = (float)v[0] + bias[200 + cg];
                pg[j][1] = (float)v[1] + bias[200 + cg + 1];
            }
            h2 dold = *(const h2*)&actG[r * 212 + 100 + (n0 >> 1)];
            float dn[2];
#pragma unroll
            for (int e = 0; e < 2; ++e) {
                float reset = sigm_(pg[0][e]);
                float cand  = tanh_(reset * pg[1][e]);
                float upd   = sigm_(pg[2][e] - 1.0f);
                dn[e] = upd * cand + (1.0f - upd) * (float)dold[e];
            }
            unsigned pk = packh2(dn[0], dn[1]);
            actG[r * 212 + 100 + (n0 >> 1)] = pk;
            ATOMIC_ST(qd + r * 100 + (n0 >> 1), pk);
            *(float2*)(out + ((size_t)(rb + r) * 64 + t) * 380 + 180 + n0) = make_float2(dn[0], dn[1]);
        }
        __syncthreads();              // drains qdet stores (vmcnt0) for all waves

        // ---- S1: deter quarter exchange ----
        __atomic_signal_fence(__ATOMIC_RELEASE);
        if (tid == 0) ATOMIC_ST(gf + t * 8 + wg, (unsigned)(t + 1));
        if (tid < 3) {
            unsigned* f = gf + t * 8 + ((wg + 1 + tid) & 3);
            int it = 0;
            while (ATOMIC_LD(f) != (unsigned)(t + 1)) {
                __builtin_amdgcn_s_sleep(1);
                if (++it > (1 << 20)) break;
            }
        }
        __syncthreads();
        __atomic_signal_fence(__ATOMIC_ACQUIRE);
        for (int i = tid; i < 1200; i += 512) {
            int r = i / 75, idx = i % 75;
            int pp = (25 * (wg + 1) + idx) % 100;
            actG[r * 212 + 100 + pp] = ATOMIC_LD(qd + r * 100 + pp);
        }
        __syncthreads();

        // ---- P3 (wg0/wg2): h/ho = elu(deter_new @ W [+ep] + b) -> actX ----
        if (statside) {
            int colA = w * 16 + m;          // <= 127
            int colB = (8 + w) * 16 + m;    // tile 8+w (w<5)
            h2 epA[4], epB[4];
            if (post && !(m & 1)) {
#pragma unroll
                for (int i = 0; i < 4; ++i)
                    epA[i] = *(const h2*)(ep + ((size_t)(rb + q * 4 + i) * 64 + t) * 208 + colA);
                if (w < 5 && colB < 200) {
#pragma unroll
                    for (int i = 0; i < 4; ++i)
                        epB[i] = *(const h2*)(ep + ((size_t)(rb + q * 4 + i) * 64 + t) * 208 + colB);
                }
            }
            f32x4 acc = {}, acc2 = {};
#pragma unroll
            for (int ks = 0; ks < 7; ++ks) {
                half8 a = *(const half8*)(actG + m * 212 + 100 + ks * 16 + q * 4);
                acc = MFMA16(a, bp3a[ks], acc);
                if (w < 5) acc2 = MFMA16(a, pf3[ks], acc2);
            }
            f32x4 accN;
#pragma unroll
            for (int i = 0; i < 4; ++i) accN[i] = __shfl_xor(acc[i], 1);
            if (!(m & 1)) {
                int bb0 = post ? 1000 : 800;
#pragma unroll
                for (int i = 0; i < 4; ++i) {
                    float e0 = post ? (float)epA[i][0] : 0.0f;
                    float e1 = post ? (float)epA[i][1] : 0.0f;
                    actX[(q * 4 + i) * 116 + (colA >> 1)] =
                        packh2(elu_(acc[i] + bias[bb0 + colA] + e0),
                               elu_(accN[i] + bias[bb0 + colA + 1] + e1));
                }
            }
            if (w < 5) {
                f32x4 acc2N;
#pragma unroll
                for (int i = 0; i < 4; ++i) acc2N[i] = __shfl_xor(acc2[i], 1);
                if (!(m & 1) && colB < 200) {
                    int bb0 = post ? 1000 : 800;
#pragma unroll
                    for (int i = 0; i < 4; ++i) {
                        float e0 = post ? (float)epB[i][0] : 0.0f;
                        float e1 = post ? (float)epB[i][1] : 0.0f;
                        actX[(q * 4 + i) * 116 + (colB >> 1)] =
                            packh2(elu_(acc2[i] + bias[bb0 + colB] + e0),
                                   elu_(acc2N[i] + bias[bb0 + colB + 1] + e1));
                    }
                }
            }
        }
        __syncthreads();

        // ---- P4 (wg0/wg2, waves 4-7): stats preacts ----
        if (statside && w >= 4) {
            f32x4 acc = {};
#pragma unroll
            for (int ks = 0; ks < 7; ++ks) {
                half8 a = *(const half8*)(actX + m * 116 + ks * 16 + q * 4);
                acc = MFMA16(a, bp4[ks], acc);
            }
#pragma unroll
            for (int i = 0; i < 4; ++i)
                statspre[(q * 4 + i) * 65 + (w - 4) * 16 + m] = acc[i];
        }
        __syncthreads();

        // ---- P5 (wg0/wg2): mean/std/stoch -> outs; wg2 publishes stoch ----
        if (statside && tid < 240) {
            int r = tid / 15, cp = tid % 15;
            int bb0 = post ? 1260 : 1200;
            float m0 = statspre[r * 65 + 2 * cp]     + bias[bb0 + 2 * cp];
            float m1 = statspre[r * 65 + 2 * cp + 1] + bias[bb0 + 2 * cp + 1];
            float s0 = sp_(statspre[r * 65 + 30 + 2 * cp]     + bias[bb0 + 30 + 2 * cp]) + 0.1f;
            float s1 = sp_(statspre[r * 65 + 30 + 2 * cp + 1] + bias[bb0 + 30 + 2 * cp + 1]) + 0.1f;
            float st0 = m0 + s0 * nz.x, st1 = m1 + s1 * nz.y;
            size_t ob = ((size_t)(rb + r) * 64 + t) * 380;
            int o0 = post ? 0 : 90;
            *(float2*)(out + ob + o0 + 2 * cp)      = make_float2(st0, st1);
            *(float2*)(out + ob + o0 + 30 + 2 * cp) = make_float2(m0, m1);
            *(float2*)(out + ob + o0 + 60 + 2 * cp) = make_float2(s0, s1);
            if (post) {
                unsigned pk = packh2(st0, st1);
                actI[r * 36 + cp] = pk;
                ATOMIC_ST(stochb + (size_t)((t & 1) * 32 + g) * 256 + r * 16 + cp, pk);
            }
        }
        __syncthreads();              // drains stochb stores
        if (wg == 2 && t < 63) {
            __atomic_signal_fence(__ATOMIC_RELEASE);
            if (tid == 0) ATOMIC_ST(gf + t * 8 + 4, (unsigned)(t + 1));
        }
    }
}

extern "C" void kernel_launch(void* const* d_in, const int* in_sizes, int n_in,
                              void* d_out, int out_size, void* d_ws, size_t ws_size,
                              hipStream_t stream) {
    const float* embed   = (const float*)d_in[0];
    const float* action  = (const float*)d_in[1];
    const float* npr     = (const float*)d_in[2];
    const float* npo     = (const float*)d_in[3];
    const float* inpW    = (const float*)d_in[4];
    const float* inpb    = (const float*)d_in[5];
    const float* gruW    = (const float*)d_in[6];
    const float* grub    = (const float*)d_in[7];
    const float* imgW    = (const float*)d_in[8];
    const float* imgb    = (const float*)d_in[9];
    const float* imsW    = (const float*)d_in[10];
    const float* imsb    = (const float*)d_in[11];
    const float* obsoutW = (const float*)d_in[12];
    const float* obsoutb = (const float*)d_in[13];
    const float* obsW    = (const float*)d_in[14];
    const float* obsb    = (const float*)d_in[15];

    char* ws = (char*)d_ws;
    _Float16* ep     = (_Float16*)ws;                              // 13,631,488 B
    _Float16* frags  = (_Float16*)(ws + EP_HALVES * 2);            // 1,202,176 B
    char* p          = ws + EP_HALVES * 2 + (size_t)1174 * 1024;
    unsigned* qdetb  = (unsigned*)p;                               // 2*32*1600*4 = 409,600 B
    p += (size_t)2 * 32 * 1600 * 4;
    unsigned* stochb = (unsigned*)p;                               // 2*32*256*4 = 65,536 B
    p += (size_t)2 * 32 * 256 * 4;
    unsigned* flags  = (unsigned*)p;                               // 32*512*4 = 65,536 B

    prep_frags<<<1174, 64, 0, stream>>>(inpW, gruW, imgW, obsoutW, imsW, obsW, frags);
    ep_gemm<<<2048, 256, 0, stream>>>(embed, frags + (size_t)758 * 512, ep);
    rssm_scan<<<128, 512, 0, stream>>>(action, npr, npo, inpb, grub, imgb, obsoutb,
                                       imsb, obsb, frags, ep, qdetb, stochb, flags,
                                       (float*)d_out);
}